// Round 9
// baseline (3360.083 us; speedup 1.0000x reference)
//
#include <hip/hip_runtime.h>
#include <hip/hip_bf16.h>

// LSTM H=1024, B=256, T=256, C=10 — round 9.
// Rounds 6/7/8 all ~12.7 us/step regardless of W residency (L2-stream vs
// scratch vs AGPR-pinned) => W was never the floor. New model: the per-step
// barrier does 32 SERIALIZED agent-scope fetch_adds on ONE cache line per
// bt-group (~700 cyc each at the remote coherence point) ~= 9-10 us/step —
// matches the gap. Fix (single variable): per-producer flag lines.
//   producer: one release STORE (step stamp t+1) to its own 128-B line —
//             32 stores in parallel, no RMW chain.
//   consumer: wave 0, lane L polls producer (L&31)'s flag with an acquire
//             load; __all() exit — one parallel round, not a chain.
// WAR-safe: consumer at step t waits flags>=t (producers finished t-1, i.e.
// finished READING buf[(t-1)&1] = the buffer written at step t). Identical
// protocol to the counter version (rounds 6-8, passed).

#define H 1024
#define B 256
#define T 256
#define NCLS 10

typedef __attribute__((ext_vector_type(8))) short short8;   // 8 bf16
typedef __attribute__((ext_vector_type(4))) float f32x4;

__device__ inline unsigned short bf16_bits(float f) {
    union { __hip_bfloat16 h; unsigned short u; } cv;
    cv.h = __float2bfloat16(f);
    return cv.u;
}

// h frag layout (per 512 KB buffer), 16x16x32 B-frag order:
//   short index of (j in [0,1024), b in [0,256)):
//   ((b>>4)*32 + (j>>5))*512 + (((j>>3)&3)*16 + (b&15))*8 + (j&7)

__global__ __launch_bounds__(512)
__attribute__((amdgpu_waves_per_eu(2, 2)))
void lstm_persist(
    const float* __restrict__ x,
    const float* __restrict__ Wgh, const float* __restrict__ Wih,
    const float* __restrict__ Wfh, const float* __restrict__ Woh,
    const float* __restrict__ Wgx, const float* __restrict__ Wix,
    const float* __restrict__ Wfx, const float* __restrict__ Wox,
    const float* __restrict__ bg, const float* __restrict__ bi,
    const float* __restrict__ bf_, const float* __restrict__ bo,
    char* __restrict__ frag,            // 2 x 524288 bytes
    unsigned* __restrict__ flags,       // 256 flags, 128-B stride (32 KB)
    float* __restrict__ hfin)           // H x B fp32
{
    __shared__ __align__(16) char hstage[65536];   // full bt h-slice (64 KB)
    __shared__ float zb[2][4][32][36];             // [khalf][gate][row][col+pad]
    __shared__ float wxl[4][32];
    __shared__ float bsl[4][32];

    const int tid  = threadIdx.x;
    const int lane = tid & 63;
    const int wave = tid >> 6;          // 0..7
    const int gate = wave & 3;
    const int kh   = wave >> 2;         // k-half: k in [512*kh, 512*kh+512)
    const int bt = blockIdx.x & 7;      // column group (XCD-local heuristic)
    const int jt = blockIdx.x >> 3;
    const int j0 = jt * 32;
    const int b0 = bt * 32;

    if (tid < 128) {
        int g = tid >> 5, r = tid & 31;
        const float* wx = (g == 0) ? Wgx : (g == 1) ? Wix : (g == 2) ? Wfx : Wox;
        const float* bb = (g == 0) ? bg  : (g == 1) ? bi  : (g == 2) ? bf_ : bo;
        wxl[g][r] = wx[j0 + r];
        bsl[g][r] = bb[b0 + r];
    }

    // ---- one-time: W gate tile -> registers, 16x16x32 A-fragment order ----
    // A map (HW-verified): lane holds A[m=lane&15][k = cg*32 + (lane>>4)*8 + i]
    const float* Wh = (gate == 0) ? Wgh : (gate == 1) ? Wih : (gate == 2) ? Wfh : Woh;
    short8 awreg[2][16];
#pragma unroll
    for (int mt = 0; mt < 2; ++mt) {
        const float* wrow = Wh + (j0 + 16 * mt + (lane & 15)) * H
                          + kh * 512 + ((lane >> 4) * 8);
#pragma unroll
        for (int c = 0; c < 16; ++c) {
            const float4 f0 = *(const float4*)(wrow + c * 32);
            const float4 f1 = *(const float4*)(wrow + c * 32 + 4);
            short8 s;
            s[0] = (short)bf16_bits(f0.x); s[1] = (short)bf16_bits(f0.y);
            s[2] = (short)bf16_bits(f0.z); s[3] = (short)bf16_bits(f0.w);
            s[4] = (short)bf16_bits(f1.x); s[5] = (short)bf16_bits(f1.y);
            s[6] = (short)bf16_bits(f1.z); s[7] = (short)bf16_bits(f1.w);
            awreg[mt][c] = s;
        }
    }
    // ---- PIN into AGPRs (round 8): opaque origin, AGPR class ----
#pragma unroll
    for (int mt = 0; mt < 2; ++mt)
#pragma unroll
        for (int c = 0; c < 16; ++c)
            __asm__ volatile("" : "+a"(awreg[mt][c]));

    float creg[2] = {0.f, 0.f};
    const int nn = tid & 31;       // epilogue column  (b = b0+nn)
    const int aa = tid >> 5;       // epilogue j-pair  (j = j0+2*aa+q), aa in [0,16)

    // this WG's flag line; producer set for the poll: WGs (lane&31)*8 + bt
    unsigned* myflag = &flags[blockIdx.x * 32];
    unsigned* pollflag = &flags[(((unsigned)lane & 31) * 8 + bt) * 32];

    for (int t = 0; t < T; ++t) {
        // x load has no dependency on the barrier — issue early, use in epilogue
        const float xv = x[(b0 + nn) * T + t];

        // ---- wait (parallel): all 32 WGs of this bt-group finished step t-1 ----
        if (wave == 0) {
            const unsigned target = (unsigned)t;
            while (true) {
                unsigned v = __hip_atomic_load(pollflag, __ATOMIC_ACQUIRE,
                                               __HIP_MEMORY_SCOPE_AGENT);
                if (__all((int)(v >= target))) break;
                __builtin_amdgcn_s_sleep(1);
            }
        }
        __syncthreads();

        // ---- stage the full 64 KB bt h-slice (linear copy) ----
        {
            const short8* gs = (const short8*)(frag + (t & 1) * 524288 + bt * 65536);
            short8* d = (short8*)hstage;
            for (int i = tid; i < 4096; i += 512) d[i] = gs[i];
        }
        __syncthreads();

        // ---- MFMA: 32 rows x 32 cols x K=512 per wave ----
        f32x4 a00 = {0.f,0.f,0.f,0.f}, a01 = a00, a10 = a00, a11 = a00;
#pragma unroll
        for (int c = 0; c < 16; ++c) {
            const int cg = kh * 16 + c;
            short8 bf0 = *(const short8*)(hstage + cg * 1024 + lane * 16);
            short8 bf1 = *(const short8*)(hstage + 32768 + cg * 1024 + lane * 16);
            a00 = __builtin_amdgcn_mfma_f32_16x16x32_bf16(awreg[0][c], bf0, a00, 0, 0, 0);
            a01 = __builtin_amdgcn_mfma_f32_16x16x32_bf16(awreg[0][c], bf1, a01, 0, 0, 0);
            a10 = __builtin_amdgcn_mfma_f32_16x16x32_bf16(awreg[1][c], bf0, a10, 0, 0, 0);
            a11 = __builtin_amdgcn_mfma_f32_16x16x32_bf16(awreg[1][c], bf1, a11, 0, 0, 0);
        }

        // C/D (HW-verified): col = lane&15, row = (lane>>4)*4 + reg
        {
            const int cn = lane & 15;
            const int rb = (lane >> 4) * 4;
#pragma unroll
            for (int r = 0; r < 4; ++r) {
                zb[kh][gate][ 0 + rb + r][ 0 + cn] = a00[r];
                zb[kh][gate][ 0 + rb + r][16 + cn] = a01[r];
                zb[kh][gate][16 + rb + r][ 0 + cn] = a10[r];
                zb[kh][gate][16 + rb + r][16 + cn] = a11[r];
            }
        }
        __syncthreads();

        // ---- elementwise epilogue: 2 cells/thread (j = j0+2*aa+q, b = b0+nn)
        unsigned short hb[2];
#pragma unroll
        for (int q = 0; q < 2; ++q) {
            const int jl = 2 * aa + q;
            float zg = (zb[0][0][jl][nn] + zb[1][0][jl][nn]) + wxl[0][jl] * xv + bsl[0][nn];
            float zi = (zb[0][1][jl][nn] + zb[1][1][jl][nn]) + wxl[1][jl] * xv + bsl[1][nn];
            float zf = (zb[0][2][jl][nn] + zb[1][2][jl][nn]) + wxl[2][jl] * xv + bsl[2][nn];
            float zo = (zb[0][3][jl][nn] + zb[1][3][jl][nn]) + wxl[3][jl] * xv + bsl[3][nn];
            float g  = tanhf(zg);
            float ig = 1.f / (1.f + expf(-zi));
            float fg = 1.f / (1.f + expf(-zf));
            float og = 1.f / (1.f + expf(-zo));
            creg[q] = g * ig + creg[q] * fg;
            float hn = tanhf(creg[q]) * og;
            hb[q] = bf16_bits(hn);
            if (t == T - 1) hfin[(j0 + jl) * B + (b0 + nn)] = hn;
        }
        // pack the 2 consecutive-j bf16 -> one 4 B store into next frag buffer
        {
            const unsigned val = (unsigned)hb[0] | ((unsigned)hb[1] << 16);
            short* fb = (short*)(frag + ((t + 1) & 1) * 524288);
            short* fdst = fb + ((2 * bt + (nn >> 4)) * 32 + jt) * 512
                        + ((aa >> 2) * 16 + (nn & 15)) * 8 + (aa & 3) * 2;
            *(unsigned*)fdst = val;
        }

        // ---- arrive: syncthreads drains every wave's stores (vmcnt(0) before
        // s_barrier); ONE release STORE (no RMW) flushes L2 + publishes t+1 ----
        __syncthreads();
        if (tid == 0)
            __hip_atomic_store(myflag, (unsigned)(t + 1), __ATOMIC_RELEASE,
                               __HIP_MEMORY_SCOPE_AGENT);
    }
}

// ---------------- projection + softmax over batch --------------------------
__global__ __launch_bounds__(256) void lstm_final(
    const float* __restrict__ Wph, const float* __restrict__ hfin,
    const float* __restrict__ bp, float* __restrict__ out)
{
    __shared__ float sh[256];
    __shared__ float shm, shs;
    int c = blockIdx.x;
    int b = threadIdx.x;
    float acc = bp[b];
    const float* wr = Wph + c * H;
    for (int k = 0; k < H; ++k)
        acc += wr[k] * hfin[k * B + b];

    sh[b] = acc;
    __syncthreads();
    for (int s = 128; s > 0; s >>= 1) {
        if (b < s) sh[b] = fmaxf(sh[b], sh[b + s]);
        __syncthreads();
    }
    if (b == 0) shm = sh[0];
    __syncthreads();
    float e = expf(acc - shm);
    sh[b] = e;
    __syncthreads();
    for (int s = 128; s > 0; s >>= 1) {
        if (b < s) sh[b] += sh[b + s];
        __syncthreads();
    }
    if (b == 0) shs = sh[0];
    __syncthreads();
    out[b * NCLS + c] = e / shs;
}

extern "C" void kernel_launch(void* const* d_in, const int* in_sizes, int n_in,
                              void* d_out, int out_size, void* d_ws, size_t ws_size,
                              hipStream_t stream)
{
    const float* x   = (const float*)d_in[0];
    const float* Wgx = (const float*)d_in[1];
    const float* Wgh = (const float*)d_in[2];
    const float* Wix = (const float*)d_in[3];
    const float* Wih = (const float*)d_in[4];
    const float* Wfx = (const float*)d_in[5];
    const float* Wfh = (const float*)d_in[6];
    const float* Wox = (const float*)d_in[7];
    const float* Woh = (const float*)d_in[8];
    const float* Wph = (const float*)d_in[9];
    const float* bg  = (const float*)d_in[10];
    const float* bi  = (const float*)d_in[11];
    const float* bfv = (const float*)d_in[12];
    const float* bo  = (const float*)d_in[13];
    const float* bp  = (const float*)d_in[14];

    char* ws = (char*)d_ws;
    char* frag = ws;                                 // 1 MB (2 x 512 KB)
    unsigned* flags = (unsigned*)(ws + 1048576);     // 32 KB (256 x 128 B)
    float* hfin = (float*)(ws + 1081344);            // 1 MB

    hipMemsetAsync(frag, 0, 524288, stream);         // h_0 = 0
    hipMemsetAsync(flags, 0, 32768, stream);         // flag lines

    lstm_persist<<<256, 512, 0, stream>>>(
        x, Wgh, Wih, Wfh, Woh, Wgx, Wix, Wfx, Wox,
        bg, bi, bfv, bo, frag, flags, hfin);

    lstm_final<<<NCLS, 256, 0, stream>>>(Wph, hfin, bp, (float*)d_out);
}

// Round 10
// 1963.028 us; speedup vs baseline: 1.7117x; 1.7117x over previous
//
#include <hip/hip_runtime.h>
#include <hip/hip_bf16.h>

// LSTM H=1024, B=256, T=256, C=10 — round 10.
// Rounds 6-9 pinned at ~13 us/step regardless of W residency, RMW-vs-flag
// sync => the constant was the acquire/release CACHE MAINTENANCE: agent
// release emits buffer_wbl2 (walks the 4 MiB L2, ~5-10 us) and acquire emits
// buffer_inv — every step, on the critical path. WRITE_SIZE ~190 MB/dispatch
// == 256 x full frag flush corroborates.
// Fix (single variable): remove acquire/release entirely. All frag + flag
// accesses are RELAXED agent-scope atomics -> sc0/sc1 (L1/L2-bypass) ops
// served at the Infinity Cache coherence point; no wbl2/inv is ever emitted.
// Ordering: producer stores -> __syncthreads (vmcnt(0) drain for all waves,
// write-acks from the coherence point) -> tid0 relaxed flag store. Consumer:
// relaxed poll -> __syncthreads -> relaxed staging loads. Frag lines are
// touched ONLY via sc1 accesses, so no stale L2 copies can exist.
// Protocol/stamps identical to rounds 6-9 (passed).

#define H 1024
#define B 256
#define T 256
#define NCLS 10

typedef __attribute__((ext_vector_type(8))) short short8;   // 8 bf16
typedef __attribute__((ext_vector_type(4))) float f32x4;

__device__ inline unsigned short bf16_bits(float f) {
    union { __hip_bfloat16 h; unsigned short u; } cv;
    cv.h = __float2bfloat16(f);
    return cv.u;
}

// h frag layout (per 512 KB buffer), 16x16x32 B-frag order:
//   short index of (j in [0,1024), b in [0,256)):
//   ((b>>4)*32 + (j>>5))*512 + (((j>>3)&3)*16 + (b&15))*8 + (j&7)

__global__ __launch_bounds__(512)
__attribute__((amdgpu_waves_per_eu(2, 2)))
void lstm_persist(
    const float* __restrict__ x,
    const float* __restrict__ Wgh, const float* __restrict__ Wih,
    const float* __restrict__ Wfh, const float* __restrict__ Woh,
    const float* __restrict__ Wgx, const float* __restrict__ Wix,
    const float* __restrict__ Wfx, const float* __restrict__ Wox,
    const float* __restrict__ bg, const float* __restrict__ bi,
    const float* __restrict__ bf_, const float* __restrict__ bo,
    char* __restrict__ frag,            // 2 x 524288 bytes
    unsigned* __restrict__ flags,       // 256 flags, 128-B stride (32 KB)
    float* __restrict__ hfin)           // H x B fp32
{
    __shared__ __align__(16) char hstage[65536];   // full bt h-slice (64 KB)
    __shared__ float zb[2][4][32][36];             // [khalf][gate][row][col+pad]
    __shared__ float wxl[4][32];
    __shared__ float bsl[4][32];

    const int tid  = threadIdx.x;
    const int lane = tid & 63;
    const int wave = tid >> 6;          // 0..7
    const int gate = wave & 3;
    const int kh   = wave >> 2;         // k-half: k in [512*kh, 512*kh+512)
    const int bt = blockIdx.x & 7;      // column group
    const int jt = blockIdx.x >> 3;
    const int j0 = jt * 32;
    const int b0 = bt * 32;

    if (tid < 128) {
        int g = tid >> 5, r = tid & 31;
        const float* wx = (g == 0) ? Wgx : (g == 1) ? Wix : (g == 2) ? Wfx : Wox;
        const float* bb = (g == 0) ? bg  : (g == 1) ? bi  : (g == 2) ? bf_ : bo;
        wxl[g][r] = wx[j0 + r];
        bsl[g][r] = bb[b0 + r];
    }

    // ---- one-time: W gate tile -> registers, 16x16x32 A-fragment order ----
    // A map (HW-verified): lane holds A[m=lane&15][k = cg*32 + (lane>>4)*8 + i]
    const float* Wh = (gate == 0) ? Wgh : (gate == 1) ? Wih : (gate == 2) ? Wfh : Woh;
    short8 awreg[2][16];
#pragma unroll
    for (int mt = 0; mt < 2; ++mt) {
        const float* wrow = Wh + (j0 + 16 * mt + (lane & 15)) * H
                          + kh * 512 + ((lane >> 4) * 8);
#pragma unroll
        for (int c = 0; c < 16; ++c) {
            const float4 f0 = *(const float4*)(wrow + c * 32);
            const float4 f1 = *(const float4*)(wrow + c * 32 + 4);
            short8 s;
            s[0] = (short)bf16_bits(f0.x); s[1] = (short)bf16_bits(f0.y);
            s[2] = (short)bf16_bits(f0.z); s[3] = (short)bf16_bits(f0.w);
            s[4] = (short)bf16_bits(f1.x); s[5] = (short)bf16_bits(f1.y);
            s[6] = (short)bf16_bits(f1.z); s[7] = (short)bf16_bits(f1.w);
            awreg[mt][c] = s;
        }
    }
    // ---- PIN into AGPRs (round 8): opaque origin, AGPR class ----
#pragma unroll
    for (int mt = 0; mt < 2; ++mt)
#pragma unroll
        for (int c = 0; c < 16; ++c)
            __asm__ volatile("" : "+a"(awreg[mt][c]));

    float creg[2] = {0.f, 0.f};
    const int nn = tid & 31;       // epilogue column  (b = b0+nn)
    const int aa = tid >> 5;       // epilogue j-pair  (j = j0+2*aa+q), aa in [0,16)

    unsigned* myflag = &flags[blockIdx.x * 32];
    unsigned* pollflag = &flags[(((unsigned)lane & 31) * 8 + bt) * 32];

    for (int t = 0; t < T; ++t) {
        // x load has no dependency on the barrier — issue early, use in epilogue
        const float xv = x[(b0 + nn) * T + t];

        // ---- wait (parallel, RELAXED): group finished step t-1 ----
        if (wave == 0) {
            const unsigned target = (unsigned)t;
            while (true) {
                unsigned v = __hip_atomic_load(pollflag, __ATOMIC_RELAXED,
                                               __HIP_MEMORY_SCOPE_AGENT);
                if (__all((int)(v >= target))) break;
                __builtin_amdgcn_s_sleep(1);
            }
        }
        __syncthreads();   // also a compiler barrier: staging can't hoist above

        // ---- stage the full 64 KB bt h-slice via RELAXED agent loads (sc1,
        // served at IC — no L2 copies of frag lines ever exist) ----
        {
            const unsigned long long* gs =
                (const unsigned long long*)(frag + (t & 1) * 524288 + bt * 65536);
            unsigned long long* d = (unsigned long long*)hstage;
#pragma unroll
            for (int k = 0; k < 16; ++k)
                d[tid + k * 512] = __hip_atomic_load(gs + tid + k * 512,
                                                     __ATOMIC_RELAXED,
                                                     __HIP_MEMORY_SCOPE_AGENT);
        }
        __syncthreads();

        // ---- MFMA: 32 rows x 32 cols x K=512 per wave ----
        f32x4 a00 = {0.f,0.f,0.f,0.f}, a01 = a00, a10 = a00, a11 = a00;
#pragma unroll
        for (int c = 0; c < 16; ++c) {
            const int cg = kh * 16 + c;
            short8 bf0 = *(const short8*)(hstage + cg * 1024 + lane * 16);
            short8 bf1 = *(const short8*)(hstage + 32768 + cg * 1024 + lane * 16);
            a00 = __builtin_amdgcn_mfma_f32_16x16x32_bf16(awreg[0][c], bf0, a00, 0, 0, 0);
            a01 = __builtin_amdgcn_mfma_f32_16x16x32_bf16(awreg[0][c], bf1, a01, 0, 0, 0);
            a10 = __builtin_amdgcn_mfma_f32_16x16x32_bf16(awreg[1][c], bf0, a10, 0, 0, 0);
            a11 = __builtin_amdgcn_mfma_f32_16x16x32_bf16(awreg[1][c], bf1, a11, 0, 0, 0);
        }

        // C/D (HW-verified): col = lane&15, row = (lane>>4)*4 + reg
        {
            const int cn = lane & 15;
            const int rb = (lane >> 4) * 4;
#pragma unroll
            for (int r = 0; r < 4; ++r) {
                zb[kh][gate][ 0 + rb + r][ 0 + cn] = a00[r];
                zb[kh][gate][ 0 + rb + r][16 + cn] = a01[r];
                zb[kh][gate][16 + rb + r][ 0 + cn] = a10[r];
                zb[kh][gate][16 + rb + r][16 + cn] = a11[r];
            }
        }
        __syncthreads();

        // ---- elementwise epilogue: 2 cells/thread (j = j0+2*aa+q, b = b0+nn)
        unsigned short hb[2];
#pragma unroll
        for (int q = 0; q < 2; ++q) {
            const int jl = 2 * aa + q;
            float zg = (zb[0][0][jl][nn] + zb[1][0][jl][nn]) + wxl[0][jl] * xv + bsl[0][nn];
            float zi = (zb[0][1][jl][nn] + zb[1][1][jl][nn]) + wxl[1][jl] * xv + bsl[1][nn];
            float zf = (zb[0][2][jl][nn] + zb[1][2][jl][nn]) + wxl[2][jl] * xv + bsl[2][nn];
            float zo = (zb[0][3][jl][nn] + zb[1][3][jl][nn]) + wxl[3][jl] * xv + bsl[3][nn];
            float g  = tanhf(zg);
            float ig = 1.f / (1.f + expf(-zi));
            float fg = 1.f / (1.f + expf(-zf));
            float og = 1.f / (1.f + expf(-zo));
            creg[q] = g * ig + creg[q] * fg;
            float hn = tanhf(creg[q]) * og;
            hb[q] = bf16_bits(hn);
            if (t == T - 1) hfin[(j0 + jl) * B + (b0 + nn)] = hn;
        }
        // pack 2 consecutive-j bf16 -> one RELAXED agent 4-B store (sc1,
        // write-through to IC; no dirty L2 lines are ever created)
        {
            const unsigned val = (unsigned)hb[0] | ((unsigned)hb[1] << 16);
            short* fb = (short*)(frag + ((t + 1) & 1) * 524288);
            short* fdst = fb + ((2 * bt + (nn >> 4)) * 32 + jt) * 512
                        + ((aa >> 2) * 16 + (nn & 15)) * 8 + (aa & 3) * 2;
            __hip_atomic_store((unsigned*)fdst, val, __ATOMIC_RELAXED,
                               __HIP_MEMORY_SCOPE_AGENT);
        }

        // ---- arrive: __syncthreads drains EVERY wave's write-acks at the
        // coherence point (compiler emits s_waitcnt vmcnt(0) before s_barrier);
        // then one RELAXED flag store — no wbl2, no inv, nothing to walk ----
        __syncthreads();
        if (tid == 0) {
            __asm__ volatile("s_waitcnt vmcnt(0)" ::: "memory");
            __hip_atomic_store(myflag, (unsigned)(t + 1), __ATOMIC_RELAXED,
                               __HIP_MEMORY_SCOPE_AGENT);
        }
    }
}

// ---------------- projection + softmax over batch --------------------------
__global__ __launch_bounds__(256) void lstm_final(
    const float* __restrict__ Wph, const float* __restrict__ hfin,
    const float* __restrict__ bp, float* __restrict__ out)
{
    __shared__ float sh[256];
    __shared__ float shm, shs;
    int c = blockIdx.x;
    int b = threadIdx.x;
    float acc = bp[b];
    const float* wr = Wph + c * H;
    for (int k = 0; k < H; ++k)
        acc += wr[k] * hfin[k * B + b];

    sh[b] = acc;
    __syncthreads();
    for (int s = 128; s > 0; s >>= 1) {
        if (b < s) sh[b] = fmaxf(sh[b], sh[b + s]);
        __syncthreads();
    }
    if (b == 0) shm = sh[0];
    __syncthreads();
    float e = expf(acc - shm);
    sh[b] = e;
    __syncthreads();
    for (int s = 128; s > 0; s >>= 1) {
        if (b < s) sh[b] += sh[b + s];
        __syncthreads();
    }
    if (b == 0) shs = sh[0];
    __syncthreads();
    out[b * NCLS + c] = e / shs;
}

extern "C" void kernel_launch(void* const* d_in, const int* in_sizes, int n_in,
                              void* d_out, int out_size, void* d_ws, size_t ws_size,
                              hipStream_t stream)
{
    const float* x   = (const float*)d_in[0];
    const float* Wgx = (const float*)d_in[1];
    const float* Wgh = (const float*)d_in[2];
    const float* Wix = (const float*)d_in[3];
    const float* Wih = (const float*)d_in[4];
    const float* Wfx = (const float*)d_in[5];
    const float* Wfh = (const float*)d_in[6];
    const float* Wox = (const float*)d_in[7];
    const float* Woh = (const float*)d_in[8];
    const float* Wph = (const float*)d_in[9];
    const float* bg  = (const float*)d_in[10];
    const float* bi  = (const float*)d_in[11];
    const float* bfv = (const float*)d_in[12];
    const float* bo  = (const float*)d_in[13];
    const float* bp  = (const float*)d_in[14];

    char* ws = (char*)d_ws;
    char* frag = ws;                                 // 1 MB (2 x 512 KB)
    unsigned* flags = (unsigned*)(ws + 1048576);     // 32 KB (256 x 128 B)
    float* hfin = (float*)(ws + 1081344);            // 1 MB

    hipMemsetAsync(frag, 0, 524288, stream);         // h_0 = 0
    hipMemsetAsync(flags, 0, 32768, stream);         // flag lines

    lstm_persist<<<256, 512, 0, stream>>>(
        x, Wgh, Wih, Wfh, Woh, Wgx, Wix, Wfx, Wox,
        bg, bi, bfv, bo, frag, flags, hfin);

    lstm_final<<<NCLS, 256, 0, stream>>>(Wph, hfin, bp, (float*)d_out);
}

// Round 11
// 1215.723 us; speedup vs baseline: 2.7639x; 1.6147x over previous
//
#include <hip/hip_runtime.h>
#include <hip/hip_bf16.h>

// LSTM H=1024, B=256, T=256, C=10 — round 11.
// Round 10 (relaxed IC-point sync, no wbl2/inv) cut 13.4 -> 7.6 us/step.
// Remaining floor theory: the 64 KB/WG staging used 8-B ATOMIC loads which
// do not coalesce at the TA -> 8192 transactions/CU/step to the IC. Fix
// (single variable): stage with inline-asm global_load_dwordx4 sc0 sc1
// (16 B/lane coalesced, still L1+L2-bypassing so frag lines never exist in
// L2 — same no-stale-line invariant as round 10), 8 loads + one
// s_waitcnt vmcnt(0), then 8 conflict-free ds_write_b128.
// Everything else identical to round 10 (passed, absmax 1.5e-5).

#define H 1024
#define B 256
#define T 256
#define NCLS 10

typedef __attribute__((ext_vector_type(8))) short short8;   // 8 bf16
typedef __attribute__((ext_vector_type(4))) float f32x4;

__device__ inline unsigned short bf16_bits(float f) {
    union { __hip_bfloat16 h; unsigned short u; } cv;
    cv.h = __float2bfloat16(f);
    return cv.u;
}

// h frag layout (per 512 KB buffer), 16x16x32 B-frag order:
//   short index of (j in [0,1024), b in [0,256)):
//   ((b>>4)*32 + (j>>5))*512 + (((j>>3)&3)*16 + (b&15))*8 + (j&7)

__global__ __launch_bounds__(512)
__attribute__((amdgpu_waves_per_eu(2, 2)))
void lstm_persist(
    const float* __restrict__ x,
    const float* __restrict__ Wgh, const float* __restrict__ Wih,
    const float* __restrict__ Wfh, const float* __restrict__ Woh,
    const float* __restrict__ Wgx, const float* __restrict__ Wix,
    const float* __restrict__ Wfx, const float* __restrict__ Wox,
    const float* __restrict__ bg, const float* __restrict__ bi,
    const float* __restrict__ bf_, const float* __restrict__ bo,
    char* __restrict__ frag,            // 2 x 524288 bytes
    unsigned* __restrict__ flags,       // 256 flags, 128-B stride (32 KB)
    float* __restrict__ hfin)           // H x B fp32
{
    __shared__ __align__(16) char hstage[65536];   // full bt h-slice (64 KB)
    __shared__ float zb[2][4][32][36];             // [khalf][gate][row][col+pad]
    __shared__ float wxl[4][32];
    __shared__ float bsl[4][32];

    const int tid  = threadIdx.x;
    const int lane = tid & 63;
    const int wave = tid >> 6;          // 0..7
    const int gate = wave & 3;
    const int kh   = wave >> 2;         // k-half: k in [512*kh, 512*kh+512)
    const int bt = blockIdx.x & 7;      // column group
    const int jt = blockIdx.x >> 3;
    const int j0 = jt * 32;
    const int b0 = bt * 32;

    if (tid < 128) {
        int g = tid >> 5, r = tid & 31;
        const float* wx = (g == 0) ? Wgx : (g == 1) ? Wix : (g == 2) ? Wfx : Wox;
        const float* bb = (g == 0) ? bg  : (g == 1) ? bi  : (g == 2) ? bf_ : bo;
        wxl[g][r] = wx[j0 + r];
        bsl[g][r] = bb[b0 + r];
    }

    // ---- one-time: W gate tile -> registers, 16x16x32 A-fragment order ----
    // A map (HW-verified): lane holds A[m=lane&15][k = cg*32 + (lane>>4)*8 + i]
    const float* Wh = (gate == 0) ? Wgh : (gate == 1) ? Wih : (gate == 2) ? Wfh : Woh;
    short8 awreg[2][16];
#pragma unroll
    for (int mt = 0; mt < 2; ++mt) {
        const float* wrow = Wh + (j0 + 16 * mt + (lane & 15)) * H
                          + kh * 512 + ((lane >> 4) * 8);
#pragma unroll
        for (int c = 0; c < 16; ++c) {
            const float4 f0 = *(const float4*)(wrow + c * 32);
            const float4 f1 = *(const float4*)(wrow + c * 32 + 4);
            short8 s;
            s[0] = (short)bf16_bits(f0.x); s[1] = (short)bf16_bits(f0.y);
            s[2] = (short)bf16_bits(f0.z); s[3] = (short)bf16_bits(f0.w);
            s[4] = (short)bf16_bits(f1.x); s[5] = (short)bf16_bits(f1.y);
            s[6] = (short)bf16_bits(f1.z); s[7] = (short)bf16_bits(f1.w);
            awreg[mt][c] = s;
        }
    }
    // ---- PIN into AGPRs (round 8): opaque origin, AGPR class ----
#pragma unroll
    for (int mt = 0; mt < 2; ++mt)
#pragma unroll
        for (int c = 0; c < 16; ++c)
            __asm__ volatile("" : "+a"(awreg[mt][c]));

    float creg[2] = {0.f, 0.f};
    const int nn = tid & 31;       // epilogue column  (b = b0+nn)
    const int aa = tid >> 5;       // epilogue j-pair  (j = j0+2*aa+q), aa in [0,16)

    unsigned* myflag = &flags[blockIdx.x * 32];
    unsigned* pollflag = &flags[(((unsigned)lane & 31) * 8 + bt) * 32];

    for (int t = 0; t < T; ++t) {
        // x load has no dependency on the barrier — issue early, use in epilogue
        const float xv = x[(b0 + nn) * T + t];

        // ---- wait (parallel, RELAXED): group finished step t-1 ----
        if (wave == 0) {
            const unsigned target = (unsigned)t;
            while (true) {
                unsigned v = __hip_atomic_load(pollflag, __ATOMIC_RELAXED,
                                               __HIP_MEMORY_SCOPE_AGENT);
                if (__all((int)(v >= target))) break;
                __builtin_amdgcn_s_sleep(1);
            }
        }
        __syncthreads();   // compiler barrier too: staging can't hoist above

        // ---- stage the full 64 KB bt h-slice: WIDE L1/L2-bypass loads ----
        // (sc0 sc1: served at the IC coherence point; frag lines never
        //  allocate in L2, preserving round 10's no-stale-line invariant)
        {
            const char* gbase = frag + (t & 1) * 524288 + bt * 65536 + tid * 16;
            short8 v0, v1, v2, v3, v4, v5, v6, v7;
            __asm__ volatile(
                "global_load_dwordx4 %0, %8, off sc0 sc1\n\t"
                "global_load_dwordx4 %1, %9, off sc0 sc1\n\t"
                "global_load_dwordx4 %2, %10, off sc0 sc1\n\t"
                "global_load_dwordx4 %3, %11, off sc0 sc1\n\t"
                "global_load_dwordx4 %4, %12, off sc0 sc1\n\t"
                "global_load_dwordx4 %5, %13, off sc0 sc1\n\t"
                "global_load_dwordx4 %6, %14, off sc0 sc1\n\t"
                "global_load_dwordx4 %7, %15, off sc0 sc1\n\t"
                "s_waitcnt vmcnt(0)"
                : "=&v"(v0), "=&v"(v1), "=&v"(v2), "=&v"(v3),
                  "=&v"(v4), "=&v"(v5), "=&v"(v6), "=&v"(v7)
                : "v"(gbase),         "v"(gbase + 8192),
                  "v"(gbase + 16384), "v"(gbase + 24576),
                  "v"(gbase + 32768), "v"(gbase + 40960),
                  "v"(gbase + 49152), "v"(gbase + 57344)
                : "memory");
            short8* dd = (short8*)hstage;        // 16-B units, conflict-free
            dd[tid +    0] = v0;  dd[tid +  512] = v1;
            dd[tid + 1024] = v2;  dd[tid + 1536] = v3;
            dd[tid + 2048] = v4;  dd[tid + 2560] = v5;
            dd[tid + 3072] = v6;  dd[tid + 3584] = v7;
        }
        __syncthreads();

        // ---- MFMA: 32 rows x 32 cols x K=512 per wave ----
        f32x4 a00 = {0.f,0.f,0.f,0.f}, a01 = a00, a10 = a00, a11 = a00;
#pragma unroll
        for (int c = 0; c < 16; ++c) {
            const int cg = kh * 16 + c;
            short8 bf0 = *(const short8*)(hstage + cg * 1024 + lane * 16);
            short8 bf1 = *(const short8*)(hstage + 32768 + cg * 1024 + lane * 16);
            a00 = __builtin_amdgcn_mfma_f32_16x16x32_bf16(awreg[0][c], bf0, a00, 0, 0, 0);
            a01 = __builtin_amdgcn_mfma_f32_16x16x32_bf16(awreg[0][c], bf1, a01, 0, 0, 0);
            a10 = __builtin_amdgcn_mfma_f32_16x16x32_bf16(awreg[1][c], bf0, a10, 0, 0, 0);
            a11 = __builtin_amdgcn_mfma_f32_16x16x32_bf16(awreg[1][c], bf1, a11, 0, 0, 0);
        }

        // C/D (HW-verified): col = lane&15, row = (lane>>4)*4 + reg
        {
            const int cn = lane & 15;
            const int rb = (lane >> 4) * 4;
#pragma unroll
            for (int r = 0; r < 4; ++r) {
                zb[kh][gate][ 0 + rb + r][ 0 + cn] = a00[r];
                zb[kh][gate][ 0 + rb + r][16 + cn] = a01[r];
                zb[kh][gate][16 + rb + r][ 0 + cn] = a10[r];
                zb[kh][gate][16 + rb + r][16 + cn] = a11[r];
            }
        }
        __syncthreads();

        // ---- elementwise epilogue: 2 cells/thread (j = j0+2*aa+q, b = b0+nn)
        unsigned short hb[2];
#pragma unroll
        for (int q = 0; q < 2; ++q) {
            const int jl = 2 * aa + q;
            float zg = (zb[0][0][jl][nn] + zb[1][0][jl][nn]) + wxl[0][jl] * xv + bsl[0][nn];
            float zi = (zb[0][1][jl][nn] + zb[1][1][jl][nn]) + wxl[1][jl] * xv + bsl[1][nn];
            float zf = (zb[0][2][jl][nn] + zb[1][2][jl][nn]) + wxl[2][jl] * xv + bsl[2][nn];
            float zo = (zb[0][3][jl][nn] + zb[1][3][jl][nn]) + wxl[3][jl] * xv + bsl[3][nn];
            float g  = tanhf(zg);
            float ig = 1.f / (1.f + expf(-zi));
            float fg = 1.f / (1.f + expf(-zf));
            float og = 1.f / (1.f + expf(-zo));
            creg[q] = g * ig + creg[q] * fg;
            float hn = tanhf(creg[q]) * og;
            hb[q] = bf16_bits(hn);
            if (t == T - 1) hfin[(j0 + jl) * B + (b0 + nn)] = hn;
        }
        // pack 2 consecutive-j bf16 -> one RELAXED agent 4-B store (sc0 sc1,
        // write-through to IC; no dirty/stale L2 lines ever exist)
        {
            const unsigned val = (unsigned)hb[0] | ((unsigned)hb[1] << 16);
            short* fb = (short*)(frag + ((t + 1) & 1) * 524288);
            short* fdst = fb + ((2 * bt + (nn >> 4)) * 32 + jt) * 512
                        + ((aa >> 2) * 16 + (nn & 15)) * 8 + (aa & 3) * 2;
            __hip_atomic_store((unsigned*)fdst, val, __ATOMIC_RELAXED,
                               __HIP_MEMORY_SCOPE_AGENT);
        }

        // ---- arrive: __syncthreads drains EVERY wave's write-acks at the
        // coherence point; then one RELAXED flag store — no wbl2/inv ----
        __syncthreads();
        if (tid == 0) {
            __asm__ volatile("s_waitcnt vmcnt(0)" ::: "memory");
            __hip_atomic_store(myflag, (unsigned)(t + 1), __ATOMIC_RELAXED,
                               __HIP_MEMORY_SCOPE_AGENT);
        }
    }
}

// ---------------- projection + softmax over batch --------------------------
__global__ __launch_bounds__(256) void lstm_final(
    const float* __restrict__ Wph, const float* __restrict__ hfin,
    const float* __restrict__ bp, float* __restrict__ out)
{
    __shared__ float sh[256];
    __shared__ float shm, shs;
    int c = blockIdx.x;
    int b = threadIdx.x;
    float acc = bp[b];
    const float* wr = Wph + c * H;
    for (int k = 0; k < H; ++k)
        acc += wr[k] * hfin[k * B + b];

    sh[b] = acc;
    __syncthreads();
    for (int s = 128; s > 0; s >>= 1) {
        if (b < s) sh[b] = fmaxf(sh[b], sh[b + s]);
        __syncthreads();
    }
    if (b == 0) shm = sh[0];
    __syncthreads();
    float e = expf(acc - shm);
    sh[b] = e;
    __syncthreads();
    for (int s = 128; s > 0; s >>= 1) {
        if (b < s) sh[b] += sh[b + s];
        __syncthreads();
    }
    if (b == 0) shs = sh[0];
    __syncthreads();
    out[b * NCLS + c] = e / shs;
}

extern "C" void kernel_launch(void* const* d_in, const int* in_sizes, int n_in,
                              void* d_out, int out_size, void* d_ws, size_t ws_size,
                              hipStream_t stream)
{
    const float* x   = (const float*)d_in[0];
    const float* Wgx = (const float*)d_in[1];
    const float* Wgh = (const float*)d_in[2];
    const float* Wix = (const float*)d_in[3];
    const float* Wih = (const float*)d_in[4];
    const float* Wfx = (const float*)d_in[5];
    const float* Wfh = (const float*)d_in[6];
    const float* Wox = (const float*)d_in[7];
    const float* Woh = (const float*)d_in[8];
    const float* Wph = (const float*)d_in[9];
    const float* bg  = (const float*)d_in[10];
    const float* bi  = (const float*)d_in[11];
    const float* bfv = (const float*)d_in[12];
    const float* bo  = (const float*)d_in[13];
    const float* bp  = (const float*)d_in[14];

    char* ws = (char*)d_ws;
    char* frag = ws;                                 // 1 MB (2 x 512 KB)
    unsigned* flags = (unsigned*)(ws + 1048576);     // 32 KB (256 x 128 B)
    float* hfin = (float*)(ws + 1081344);            // 1 MB

    hipMemsetAsync(frag, 0, 524288, stream);         // h_0 = 0
    hipMemsetAsync(flags, 0, 32768, stream);         // flag lines

    lstm_persist<<<256, 512, 0, stream>>>(
        x, Wgh, Wih, Wfh, Woh, Wgx, Wix, Wfx, Wox,
        bg, bi, bfv, bo, frag, flags, hfin);

    lstm_final<<<NCLS, 256, 0, stream>>>(Wph, hfin, bp, (float*)d_out);
}

// Round 13
// 1160.280 us; speedup vs baseline: 2.8959x; 1.0478x over previous
//
#include <hip/hip_runtime.h>
#include <hip/hip_bf16.h>

// LSTM H=1024, B=256, T=256, C=10 — round 13.
// Round 12 (global XCD rendezvous + L2 flags) died at infra level — two new
// hazard surfaces: a 256-WG discovery barrier, and L2-resident flags/h0 that
// hipMemsetAsync cannot reliably clear (stale dirty lines in remote XCD L2s
// survive the memset). Round 13 keeps the PROVEN round-11 skeleton:
//  - flags: ALWAYS round-11 IC protocol (agent relaxed, no L2 copies, memset
//    zeros visible) — sync protocol untouched.
//  - h exchange only: per-GROUP locality detection (publish XCC_ID+1 via IC,
//    group-polls its own 32 slots — same co-residency assumption as the
//    per-step barrier, proven in rounds 5-11; all members reach the same
//    all-equal verdict). Local -> plain write-back h stores + sc0 loads
//    (XCD-L2 exchange); non-local -> byte-identical round-11 sc0sc1 path.
//  - t=0 skips staging+MFMA (h0==0 => z==0): NO read of uninitialized frag,
//    so no dependence on memset vs stale-L2 state, and frag memset dropped.
//  - fast gates via v_exp_f32 / v_rcp_f32 (~1e-7 rel err << bf16 noise).

#define H 1024
#define B 256
#define T 256
#define NCLS 10

typedef __attribute__((ext_vector_type(8))) short short8;   // 8 bf16
typedef __attribute__((ext_vector_type(4))) float f32x4;

__device__ inline unsigned short bf16_bits(float f) {
    union { __hip_bfloat16 h; unsigned short u; } cv;
    cv.h = __float2bfloat16(f);
    return cv.u;
}

#define L2E 1.4426950408889634f
__device__ inline float sigm_fast(float x) {
    float e = __builtin_amdgcn_exp2f(-L2E * x);
    return __builtin_amdgcn_rcpf(1.0f + e);
}
__device__ inline float tanh_fast(float x) {
    float e = __builtin_amdgcn_exp2f((2.0f * L2E) * x);     // e^(2x)
    return 1.0f - 2.0f * __builtin_amdgcn_rcpf(1.0f + e);   // +-sat correct
}

// h frag layout (per 512 KB buffer), 16x16x32 B-frag order:
//   short index of (j in [0,1024), b in [0,256)):
//   ((b>>4)*32 + (j>>5))*512 + (((j>>3)&3)*16 + (b&15))*8 + (j&7)

__global__ __launch_bounds__(512)
__attribute__((amdgpu_waves_per_eu(2, 2)))
void lstm_persist(
    const float* __restrict__ x,
    const float* __restrict__ Wgh, const float* __restrict__ Wih,
    const float* __restrict__ Wfh, const float* __restrict__ Woh,
    const float* __restrict__ Wgx, const float* __restrict__ Wix,
    const float* __restrict__ Wfx, const float* __restrict__ Wox,
    const float* __restrict__ bg, const float* __restrict__ bi,
    const float* __restrict__ bf_, const float* __restrict__ bo,
    char* __restrict__ frag,            // 2 x 524288 bytes (NOT pre-zeroed)
    unsigned* __restrict__ flags,       // 256 flag lines, 128-B stride (IC)
    unsigned* __restrict__ det,         // 256 slots x 4B (IC), zeroed
    float* __restrict__ hfin)           // H x B fp32
{
    __shared__ __align__(16) char hstage[65536];   // full bt h-slice (64 KB)
    __shared__ float zb[2][4][32][36];             // [khalf][gate][row][col+pad]
    __shared__ float wxl[4][32];
    __shared__ float bsl[4][32];
    __shared__ int sh_lcl;

    const int tid  = threadIdx.x;
    const int lane = tid & 63;
    const int wave = tid >> 6;          // 0..7
    const int gate = wave & 3;
    const int kh   = wave >> 2;         // k-half
    const int bt = blockIdx.x & 7;      // work mapping == round 11 (unchanged)
    const int jt = blockIdx.x >> 3;
    const int j0 = jt * 32;
    const int b0 = bt * 32;

    // ---- one-time: publish my physical XCD id to my group's det slot ----
    unsigned xcc;
    __asm__ volatile("s_getreg_b32 %0, hwreg(HW_REG_XCC_ID)" : "=s"(xcc));
    xcc &= 7u;
    if (tid == 0)
        __hip_atomic_store(&det[bt * 32 + jt], xcc + 1u,
                           __ATOMIC_RELAXED, __HIP_MEMORY_SCOPE_AGENT);

    if (tid < 128) {
        int g = tid >> 5, r = tid & 31;
        const float* wx = (g == 0) ? Wgx : (g == 1) ? Wix : (g == 2) ? Wfx : Wox;
        const float* bb = (g == 0) ? bg  : (g == 1) ? bi  : (g == 2) ? bf_ : bo;
        wxl[g][r] = wx[j0 + r];
        bsl[g][r] = bb[b0 + r];
    }

    // ---- one-time: W gate tile -> registers, 16x16x32 A-fragment order ----
    const float* Wh = (gate == 0) ? Wgh : (gate == 1) ? Wih : (gate == 2) ? Wfh : Woh;
    short8 awreg[2][16];
#pragma unroll
    for (int mt = 0; mt < 2; ++mt) {
        const float* wrow = Wh + (j0 + 16 * mt + (lane & 15)) * H
                          + kh * 512 + ((lane >> 4) * 8);
#pragma unroll
        for (int c = 0; c < 16; ++c) {
            const float4 f0 = *(const float4*)(wrow + c * 32);
            const float4 f1 = *(const float4*)(wrow + c * 32 + 4);
            short8 s;
            s[0] = (short)bf16_bits(f0.x); s[1] = (short)bf16_bits(f0.y);
            s[2] = (short)bf16_bits(f0.z); s[3] = (short)bf16_bits(f0.w);
            s[4] = (short)bf16_bits(f1.x); s[5] = (short)bf16_bits(f1.y);
            s[6] = (short)bf16_bits(f1.z); s[7] = (short)bf16_bits(f1.w);
            awreg[mt][c] = s;
        }
    }
#pragma unroll
    for (int mt = 0; mt < 2; ++mt)
#pragma unroll
        for (int c = 0; c < 16; ++c)
            __asm__ volatile("" : "+a"(awreg[mt][c]));

    // ---- one-time: group locality verdict (poll my group's 32 det slots) ----
    if (wave == 0) {
        unsigned v;
        while (true) {
            v = __hip_atomic_load(&det[bt * 32 + (lane & 31)],
                                  __ATOMIC_RELAXED, __HIP_MEMORY_SCOPE_AGENT);
            if (__all((int)(v != 0u))) break;
            __builtin_amdgcn_s_sleep(1);
        }
        int same = __all((int)(v == xcc + 1u));
        if (tid == 0) sh_lcl = same;
    }
    __syncthreads();
    const bool lcl = (sh_lcl != 0);

    float creg[2] = {0.f, 0.f};
    const int nn = tid & 31;
    const int aa = tid >> 5;

    unsigned* myflag = &flags[blockIdx.x * 32];
    unsigned* pollflag = &flags[(((unsigned)lane & 31) * 8 + bt) * 32];

    for (int t = 0; t < T; ++t) {
        const float xv = x[(b0 + nn) * T + t];

        // ---- wait (round-11 IC protocol, unchanged) ----
        if (wave == 0) {
            const unsigned target = (unsigned)t;
            while (true) {
                unsigned v = __hip_atomic_load(pollflag, __ATOMIC_RELAXED,
                                               __HIP_MEMORY_SCOPE_AGENT);
                if (__all((int)(v >= target))) break;
                __builtin_amdgcn_s_sleep(1);
            }
        }
        __syncthreads();

        f32x4 a00 = {0.f,0.f,0.f,0.f}, a01 = a00, a10 = a00, a11 = a00;

        if (t > 0) {        // h_0 == 0 -> z == 0: skip staging+MFMA at t=0
            // ---- stage the full 64 KB bt h-slice, wide coalesced loads ----
            {
                const char* gbase = frag + (t & 1) * 524288 + bt * 65536 + tid * 16;
                short8 v0, v1, v2, v3, v4, v5, v6, v7;
                if (lcl) {   // XCD-local: L2 exchange (sc0 = L1 bypass only)
                    __asm__ volatile(
                        "global_load_dwordx4 %0, %8, off sc0\n\t"
                        "global_load_dwordx4 %1, %9, off sc0\n\t"
                        "global_load_dwordx4 %2, %10, off sc0\n\t"
                        "global_load_dwordx4 %3, %11, off sc0\n\t"
                        "global_load_dwordx4 %4, %12, off sc0\n\t"
                        "global_load_dwordx4 %5, %13, off sc0\n\t"
                        "global_load_dwordx4 %6, %14, off sc0\n\t"
                        "global_load_dwordx4 %7, %15, off sc0\n\t"
                        "s_waitcnt vmcnt(0)"
                        : "=&v"(v0), "=&v"(v1), "=&v"(v2), "=&v"(v3),
                          "=&v"(v4), "=&v"(v5), "=&v"(v6), "=&v"(v7)
                        : "v"(gbase),         "v"(gbase + 8192),
                          "v"(gbase + 16384), "v"(gbase + 24576),
                          "v"(gbase + 32768), "v"(gbase + 40960),
                          "v"(gbase + 49152), "v"(gbase + 57344)
                        : "memory");
                } else {     // round-11 IC path (proven)
                    __asm__ volatile(
                        "global_load_dwordx4 %0, %8, off sc0 sc1\n\t"
                        "global_load_dwordx4 %1, %9, off sc0 sc1\n\t"
                        "global_load_dwordx4 %2, %10, off sc0 sc1\n\t"
                        "global_load_dwordx4 %3, %11, off sc0 sc1\n\t"
                        "global_load_dwordx4 %4, %12, off sc0 sc1\n\t"
                        "global_load_dwordx4 %5, %13, off sc0 sc1\n\t"
                        "global_load_dwordx4 %6, %14, off sc0 sc1\n\t"
                        "global_load_dwordx4 %7, %15, off sc0 sc1\n\t"
                        "s_waitcnt vmcnt(0)"
                        : "=&v"(v0), "=&v"(v1), "=&v"(v2), "=&v"(v3),
                          "=&v"(v4), "=&v"(v5), "=&v"(v6), "=&v"(v7)
                        : "v"(gbase),         "v"(gbase + 8192),
                          "v"(gbase + 16384), "v"(gbase + 24576),
                          "v"(gbase + 32768), "v"(gbase + 40960),
                          "v"(gbase + 49152), "v"(gbase + 57344)
                        : "memory");
                }
                short8* dd = (short8*)hstage;
                dd[tid +    0] = v0;  dd[tid +  512] = v1;
                dd[tid + 1024] = v2;  dd[tid + 1536] = v3;
                dd[tid + 2048] = v4;  dd[tid + 2560] = v5;
                dd[tid + 3072] = v6;  dd[tid + 3584] = v7;
            }
            __syncthreads();

            // ---- MFMA: 32 rows x 32 cols x K=512 per wave ----
#pragma unroll
            for (int c = 0; c < 16; ++c) {
                const int cg = kh * 16 + c;
                short8 bf0 = *(const short8*)(hstage + cg * 1024 + lane * 16);
                short8 bf1 = *(const short8*)(hstage + 32768 + cg * 1024 + lane * 16);
                a00 = __builtin_amdgcn_mfma_f32_16x16x32_bf16(awreg[0][c], bf0, a00, 0, 0, 0);
                a01 = __builtin_amdgcn_mfma_f32_16x16x32_bf16(awreg[0][c], bf1, a01, 0, 0, 0);
                a10 = __builtin_amdgcn_mfma_f32_16x16x32_bf16(awreg[1][c], bf0, a10, 0, 0, 0);
                a11 = __builtin_amdgcn_mfma_f32_16x16x32_bf16(awreg[1][c], bf1, a11, 0, 0, 0);
            }
        }

        // C/D (HW-verified): col = lane&15, row = (lane>>4)*4 + reg
        {
            const int cn = lane & 15;
            const int rb = (lane >> 4) * 4;
#pragma unroll
            for (int r = 0; r < 4; ++r) {
                zb[kh][gate][ 0 + rb + r][ 0 + cn] = a00[r];
                zb[kh][gate][ 0 + rb + r][16 + cn] = a01[r];
                zb[kh][gate][16 + rb + r][ 0 + cn] = a10[r];
                zb[kh][gate][16 + rb + r][16 + cn] = a11[r];
            }
        }
        __syncthreads();

        // ---- elementwise epilogue: 2 cells/thread ----
        unsigned short hb[2];
#pragma unroll
        for (int q = 0; q < 2; ++q) {
            const int jl = 2 * aa + q;
            float zg = (zb[0][0][jl][nn] + zb[1][0][jl][nn]) + wxl[0][jl] * xv + bsl[0][nn];
            float zi = (zb[0][1][jl][nn] + zb[1][1][jl][nn]) + wxl[1][jl] * xv + bsl[1][nn];
            float zf = (zb[0][2][jl][nn] + zb[1][2][jl][nn]) + wxl[2][jl] * xv + bsl[2][nn];
            float zo = (zb[0][3][jl][nn] + zb[1][3][jl][nn]) + wxl[3][jl] * xv + bsl[3][nn];
            float g  = tanh_fast(zg);
            float ig = sigm_fast(zi);
            float fg = sigm_fast(zf);
            float og = sigm_fast(zo);
            creg[q] = g * ig + creg[q] * fg;
            float hn = tanh_fast(creg[q]) * og;
            hb[q] = bf16_bits(hn);
            if (t == T - 1) hfin[(j0 + jl) * B + (b0 + nn)] = hn;
        }
        // h store into next frag buffer: L2 write-back if local, else IC
        {
            const unsigned val = (unsigned)hb[0] | ((unsigned)hb[1] << 16);
            short* fb = (short*)(frag + ((t + 1) & 1) * 524288);
            short* fdst = fb + ((2 * bt + (nn >> 4)) * 32 + jt) * 512
                        + ((aa >> 2) * 16 + (nn & 15)) * 8 + (aa & 3) * 2;
            if (lcl) {
                *(volatile unsigned*)fdst = val;
            } else {
                __hip_atomic_store((unsigned*)fdst, val, __ATOMIC_RELAXED,
                                   __HIP_MEMORY_SCOPE_AGENT);
            }
        }

        // ---- arrive (round-11 IC protocol, unchanged): barrier drains every
        // wave's store-acks (L2 or IC), then one IC flag store ----
        __syncthreads();
        if (tid == 0) {
            __asm__ volatile("s_waitcnt vmcnt(0)" ::: "memory");
            __hip_atomic_store(myflag, (unsigned)(t + 1), __ATOMIC_RELAXED,
                               __HIP_MEMORY_SCOPE_AGENT);
        }
    }
}

// ---------------- projection + softmax over batch --------------------------
__global__ __launch_bounds__(256) void lstm_final(
    const float* __restrict__ Wph, const float* __restrict__ hfin,
    const float* __restrict__ bp, float* __restrict__ out)
{
    __shared__ float sh[256];
    __shared__ float shm, shs;
    int c = blockIdx.x;
    int b = threadIdx.x;
    float acc = bp[b];
    const float* wr = Wph + c * H;
    for (int k = 0; k < H; ++k)
        acc += wr[k] * hfin[k * B + b];

    sh[b] = acc;
    __syncthreads();
    for (int s = 128; s > 0; s >>= 1) {
        if (b < s) sh[b] = fmaxf(sh[b], sh[b + s]);
        __syncthreads();
    }
    if (b == 0) shm = sh[0];
    __syncthreads();
    float e = expf(acc - shm);
    sh[b] = e;
    __syncthreads();
    for (int s = 128; s > 0; s >>= 1) {
        if (b < s) sh[b] += sh[b + s];
        __syncthreads();
    }
    if (b == 0) shs = sh[0];
    __syncthreads();
    out[b * NCLS + c] = e / shs;
}

extern "C" void kernel_launch(void* const* d_in, const int* in_sizes, int n_in,
                              void* d_out, int out_size, void* d_ws, size_t ws_size,
                              hipStream_t stream)
{
    const float* x   = (const float*)d_in[0];
    const float* Wgx = (const float*)d_in[1];
    const float* Wgh = (const float*)d_in[2];
    const float* Wix = (const float*)d_in[3];
    const float* Wih = (const float*)d_in[4];
    const float* Wfx = (const float*)d_in[5];
    const float* Wfh = (const float*)d_in[6];
    const float* Wox = (const float*)d_in[7];
    const float* Woh = (const float*)d_in[8];
    const float* Wph = (const float*)d_in[9];
    const float* bg  = (const float*)d_in[10];
    const float* bi  = (const float*)d_in[11];
    const float* bfv = (const float*)d_in[12];
    const float* bo  = (const float*)d_in[13];
    const float* bp  = (const float*)d_in[14];

    char* ws = (char*)d_ws;
    char* frag = ws;                                 // 1 MB (2 x 512 KB)
    unsigned* flags = (unsigned*)(ws + 1048576);     // 32 KB (256 x 128 B)
    unsigned* det   = (unsigned*)(ws + 1081344);     // 4 KB (256 x 4 B)
    float* hfin = (float*)(ws + 1085440);            // 1 MB

    // flags+det zeroed via IC-visible memset; frag needs no init (t=0 skip)
    hipMemsetAsync(flags, 0, 36864, stream);

    lstm_persist<<<256, 512, 0, stream>>>(
        x, Wgh, Wih, Wfh, Woh, Wgx, Wix, Wfx, Wox,
        bg, bi, bfv, bo, frag, flags, det, hfin);

    lstm_final<<<NCLS, 256, 0, stream>>>(Wph, hfin, bp, (float*)d_out);
}